// Round 1
// 769.431 us; speedup vs baseline: 1.0032x; 1.0032x over previous
//
#include <hip/hip_runtime.h>

#define EMB_DIM   300
#define ROW_F4    75            // 300 floats = 75 float4; row stride 1200 B
#define TAIL_F4   (ROW_F4 - 64) // 11 tail chunks, owned by lanes 0..10
#define ROW_BYTES (EMB_DIM * 4) // 1200

// Phase 1: find segment start offsets (seg_ids sorted, every segment nonempty).
__global__ __launch_bounds__(256) void seg_starts_kernel(
        const int* __restrict__ seg, int T, int S, int* __restrict__ starts) {
    int t = blockIdx.x * 256 + threadIdx.x;
    if (t >= T) return;
    if (t == 0) {
        starts[0] = 0;
        starts[S] = T;          // end sentinel
    } else if (seg[t] != seg[t - 1]) {
        starts[seg[t]] = t;
    }
}

// Batched gather: NR rows, 2*NR loads in flight, branchless tail.
template <int NR>
__device__ __forceinline__ void gather_batch(
        const char* __restrict__ embb, int my_id, int j,
        int lane, unsigned tailOff,
        float4& acc, float4& accT) {
    const char* r[NR];
    #pragma unroll
    for (int k = 0; k < NR; ++k) {
        const int id = __shfl(my_id, j + k);
        r[k] = embb + (unsigned)id * (unsigned)ROW_BYTES;
    }
    float4 m[NR], t[NR];
    #pragma unroll
    for (int k = 0; k < NR; ++k) {
        m[k] = ((const float4*)r[k])[lane];                      // chunks 0..63
        t[k] = *(const float4*)(r[k] + tailOff);                 // chunk 64+min(lane,10)
    }
    #pragma unroll
    for (int k = 0; k < NR; ++k) {
        acc.x  += m[k].x; acc.y  += m[k].y; acc.z  += m[k].z; acc.w  += m[k].w;
        accT.x += t[k].x; accT.y += t[k].y; accT.z += t[k].z; accT.w += t[k].w;
    }
}

// Phase 2: one wave per segment; deep-MLP batched row gather.
__global__ __launch_bounds__(256) void emb_seg_mean_v2_kernel(
        const float* __restrict__ emb,       // [VOCAB, 300]
        const int*   __restrict__ word_ids,  // [T]
        const int*   __restrict__ starts,    // [S+1]
        float*       __restrict__ out,       // [S, 300]
        int num_segments) {
    const int lane = threadIdx.x & 63;
    const int s    = blockIdx.x * 4 + (threadIdx.x >> 6);
    if (s >= num_segments) return;

    const int start = starts[s];
    const int end   = starts[s + 1];
    const int count = end - start;

    // coalesced preload of up to 64 word ids; broadcast via shfl
    int my_id = 0;
    if (start + lane < end) my_id = word_ids[start + lane];

    // Branchless tail: lanes >= 11 re-read chunk 74 (same line as lane 10's
    // chunk — coalesces, zero extra HBM traffic); their accT is never stored.
    const bool tl = lane < TAIL_F4;
    const unsigned tailChunk = 64u + (unsigned)(tl ? lane : (TAIL_F4 - 1));
    const unsigned tailOff   = tailChunk * 16u;

    const char* embb = (const char*)emb;
    float4 acc  = make_float4(0.f, 0.f, 0.f, 0.f);
    float4 accT = make_float4(0.f, 0.f, 0.f, 0.f);

    const int nb = count < 64 ? count : 64;
    int j = 0;
    for (; j + 10 <= nb; j += 10)   // count==20 => exactly two batches
        gather_batch<10>(embb, my_id, j, lane, tailOff, acc, accT);
    for (; j + 4 <= nb; j += 4)
        gather_batch<4>(embb, my_id, j, lane, tailOff, acc, accT);
    for (; j < nb; ++j)
        gather_batch<1>(embb, my_id, j, lane, tailOff, acc, accT);

    // generic fallback for segments longer than 64 words (not hit in this bench)
    for (int w = start + 64; w < end; ++w) {
        const int id = word_ids[w];
        const char* r = embb + (unsigned)id * (unsigned)ROW_BYTES;
        float4 a = ((const float4*)r)[lane];
        float4 t = *(const float4*)(r + tailOff);
        acc.x  += a.x; acc.y  += a.y; acc.z  += a.z; acc.w  += a.w;
        accT.x += t.x; accT.y += t.y; accT.z += t.z; accT.w += t.w;
    }

    const float inv = 1.0f / (float)count;
    float4* __restrict__ orow = (float4*)(out + (size_t)s * EMB_DIM);
    orow[lane] = make_float4(acc.x * inv, acc.y * inv, acc.z * inv, acc.w * inv);
    if (tl)
        orow[64 + lane] = make_float4(accT.x * inv, accT.y * inv,
                                      accT.z * inv, accT.w * inv);
}

extern "C" void kernel_launch(void* const* d_in, const int* in_sizes, int n_in,
                              void* d_out, int out_size, void* d_ws, size_t ws_size,
                              hipStream_t stream) {
    const float* emb      = (const float*)d_in[0];
    const int*   word_ids = (const int*)d_in[1];
    const int*   seg_ids  = (const int*)d_in[2];
    float* out = (float*)d_out;
    int* starts = (int*)d_ws;            // S+1 ints of scratch

    const int T = in_sizes[1];
    const int S = out_size / EMB_DIM;

    seg_starts_kernel<<<(T + 255) / 256, 256, 0, stream>>>(seg_ids, T, S, starts);

    const int blocks = (S + 3) / 4;      // 4 segments (waves) per 256-thread block
    emb_seg_mean_v2_kernel<<<blocks, 256, 0, stream>>>(emb, word_ids, starts, out, S);
}